// Round 4
// baseline (312.462 us; speedup 1.0000x reference)
//
#include <hip/hip_runtime.h>
#include <stdint.h>

typedef unsigned short u16;
typedef __attribute__((ext_vector_type(8))) __bf16 bf8v;    // A/B fragment: 8 bf16
typedef __attribute__((ext_vector_type(4))) float f4v;      // 16x16 C/D
typedef __attribute__((ext_vector_type(16))) float f16v;    // 32x32 C/D
typedef __attribute__((ext_vector_type(4))) uint32_t u32x4;

#define BB 2
#define SS 2048
#define HH 1024

// workspace layout (bytes) — extent 56688640.
#define OFF_Q   0u          // Q bf16 [4096][1024]; later attn output (same region)
#define OFF_K0  8388608u
#define OFF_V0  24117248u
#define OFF_V1  32505856u
#define OFF_V2  36700160u
#define OFF_V3  38797312u
#define OFF_WQT 39845888u   // Wqkv^T bf16 [3072][1024]  (6 MB)
#define OFF_WOT 46137344u   // Wout^T bf16 [1024][1024]  (2 MB)
#define OFF_XB  48234496u   // x bf16 [4096][1024]       (8 MB)
#define OFF_SCW 56623104u   // scale weights f32 [4096][4] (64 KB)

__device__ __forceinline__ u16 f2bf(float f) {
    union { float f; uint32_t u; } v; v.f = f;
    uint32_t r = v.u + 0x7fffu + ((v.u >> 16) & 1u);   // RNE
    return (u16)(r >> 16);
}
__device__ __forceinline__ uint32_t pk2(float a, float b) {
    return (uint32_t)f2bf(a) | ((uint32_t)f2bf(b) << 16);
}
// truncation pack (2 VALU): low half <- bf-trunc(a), high half <- bf-trunc(b)
__device__ __forceinline__ uint32_t pkt2(float a, float b) {
    union { float f; uint32_t u; } x, y; x.f = a; y.f = b;
    return (x.u >> 16) | (y.u & 0xffff0000u);
}

// ---------------- x f32 -> bf16 ----------------
__global__ __launch_bounds__(256) void xconv_kernel(const float* __restrict__ x,
                                                    u16* __restrict__ xb) {
    size_t t = (size_t)blockIdx.x * 256 + threadIdx.x;
    float4 v = *(const float4*)&x[t * 4];
    uint2 pk; pk.x = pk2(v.x, v.y); pk.y = pk2(v.z, v.w);
    *(uint2*)&xb[t * 4] = pk;
}

// ---------------- W f32 [K][N] -> bf16 W^T [N][K] ----------------
__global__ __launch_bounds__(256) void wconv_kernel(const float* __restrict__ W,
                                                    u16* __restrict__ Wt,
                                                    int N, int K) {
    __shared__ float tile[64][69];
    const int tid = threadIdx.x;
    const int n0 = blockIdx.x * 64, k0 = blockIdx.y * 64;
    const int r = tid >> 4, c4 = (tid & 15) * 4;
#pragma unroll
    for (int it = 0; it < 4; it++) {
        float4 v = *(const float4*)&W[(size_t)(k0 + it * 16 + r) * N + n0 + c4];
        tile[it * 16 + r][c4 + 0] = v.x; tile[it * 16 + r][c4 + 1] = v.y;
        tile[it * 16 + r][c4 + 2] = v.z; tile[it * 16 + r][c4 + 3] = v.w;
    }
    __syncthreads();
#pragma unroll
    for (int it = 0; it < 4; it++) {
        int n = it * 16 + r;
        uint2 pk;
        pk.x = pk2(tile[c4 + 0][n], tile[c4 + 1][n]);
        pk.y = pk2(tile[c4 + 2][n], tile[c4 + 3][n]);
        *(uint2*)&Wt[(size_t)(n0 + n) * K + k0 + c4] = pk;
    }
}

// ---------------- scale weights: softmax(x @ Wscale + bscale) ----------------
__global__ __launch_bounds__(256) void scale_kernel(const float* __restrict__ x,
                                                    const float* __restrict__ Wscale,
                                                    const float* __restrict__ bscale,
                                                    float* __restrict__ scw) {
    const int lane = threadIdx.x & 63;
    const int wid  = threadIdx.x >> 6;
    const int row  = blockIdx.x * 4 + wid;
    float a0 = 0.f, a1 = 0.f, a2 = 0.f, a3 = 0.f;
    for (int i = 0; i < 16; i++) {
        int hh = lane + i * 64;
        float xs = x[(size_t)row * HH + hh];
        float4 wv = *(const float4*)&Wscale[hh * 4];
        a0 += xs * wv.x; a1 += xs * wv.y; a2 += xs * wv.z; a3 += xs * wv.w;
    }
    for (int off = 1; off < 64; off <<= 1) {
        a0 += __shfl_xor(a0, off); a1 += __shfl_xor(a1, off);
        a2 += __shfl_xor(a2, off); a3 += __shfl_xor(a3, off);
    }
    if (lane == 0) {
        a0 += bscale[0]; a1 += bscale[1]; a2 += bscale[2]; a3 += bscale[3];
        float mx = fmaxf(fmaxf(a0, a1), fmaxf(a2, a3));
        float e0 = __expf(a0 - mx), e1 = __expf(a1 - mx);
        float e2 = __expf(a2 - mx), e3 = __expf(a3 - mx);
        float inv = 1.f / (e0 + e1 + e2 + e3);
        float4 o = {e0 * inv, e1 * inv, e2 * inv, e3 * inv};
        *(float4*)&scw[(size_t)row * 4] = o;
    }
}

// ---------------- bf16 MFMA GEMM, A bf16, B pre-transposed bf16 ----------------
// MODE 0: C[M,N] f32 = A@B + bias.  MODE 1: QKV scatter epilogue.
// K scaled by 1/sqrt(64) * log2(e) so attn can use exp2 directly.
// V0/V1/V2 stored KEY-PERMUTED (within 16-blocks) so attn PV B-fragments are
// lane-local (permuting the MFMA contraction index identically on both
// operands leaves the product unchanged).
template<int MODE>
__global__ __launch_bounds__(256) void gemm_bt(const u16* __restrict__ A,
                                               const u16* __restrict__ Bt,
                                               const float* __restrict__ bias,
                                               void* __restrict__ Cp,
                                               int N, int K) {
    __shared__ __align__(16) u16 At[128 * 40];
    __shared__ __align__(16) u16 Btl[128 * 40];
    const int tid  = threadIdx.x;
    const int lane = tid & 63;
    const int wid  = tid >> 6;
    const int l15  = lane & 15;
    const int quad = lane >> 4;
    const int wm = wid & 1, wn = wid >> 1;
    const int m0 = blockIdx.y * 128;
    const int n0 = blockIdx.x * 128;
    const int srow = tid >> 2;           // 0..63
    const int sc8  = (tid & 3) * 8;      // 0,8,16,24

    f4v acc[4][4];
#pragma unroll
    for (int i = 0; i < 4; i++)
#pragma unroll
        for (int j = 0; j < 4; j++) acc[i][j] = (f4v){0.f, 0.f, 0.f, 0.f};

    uint4 pa0 = *(const uint4*)(A  + (size_t)(m0 + srow) * K + sc8);
    uint4 pa1 = *(const uint4*)(A  + (size_t)(m0 + srow + 64) * K + sc8);
    uint4 pb0 = *(const uint4*)(Bt + (size_t)(n0 + srow) * K + sc8);
    uint4 pb1 = *(const uint4*)(Bt + (size_t)(n0 + srow + 64) * K + sc8);

    for (int kc = 0; kc < K; kc += 32) {
        __syncthreads();
        *(uint4*)&At[srow * 40 + sc8]         = pa0;
        *(uint4*)&At[(srow + 64) * 40 + sc8]  = pa1;
        *(uint4*)&Btl[srow * 40 + sc8]        = pb0;
        *(uint4*)&Btl[(srow + 64) * 40 + sc8] = pb1;
        __syncthreads();
        if (kc + 32 < K) {
            pa0 = *(const uint4*)(A  + (size_t)(m0 + srow) * K + kc + 32 + sc8);
            pa1 = *(const uint4*)(A  + (size_t)(m0 + srow + 64) * K + kc + 32 + sc8);
            pb0 = *(const uint4*)(Bt + (size_t)(n0 + srow) * K + kc + 32 + sc8);
            pb1 = *(const uint4*)(Bt + (size_t)(n0 + srow + 64) * K + kc + 32 + sc8);
        }
        bf8v af[4], bf[4];
#pragma unroll
        for (int t = 0; t < 4; t++) {
            af[t] = *(const bf8v*)&At[(wm * 64 + t * 16 + l15) * 40 + quad * 8];
            bf[t] = *(const bf8v*)&Btl[(wn * 64 + t * 16 + l15) * 40 + quad * 8];
        }
#pragma unroll
        for (int ti = 0; ti < 4; ti++)
#pragma unroll
            for (int tj = 0; tj < 4; tj++)
                acc[ti][tj] = __builtin_amdgcn_mfma_f32_16x16x32_bf16(af[ti], bf[tj], acc[ti][tj], 0, 0, 0);
    }

    if (MODE == 0) {
#pragma unroll
        for (int ti = 0; ti < 4; ti++)
#pragma unroll
            for (int tj = 0; tj < 4; tj++)
#pragma unroll
                for (int r = 0; r < 4; r++) {
                    int m = m0 + wm * 64 + ti * 16 + quad * 4 + r;
                    int n = n0 + wn * 64 + tj * 16 + l15;
                    ((float*)Cp)[(size_t)m * N + n] = acc[ti][tj][r] + bias[n];
                }
    } else {
        char* ws = (char*)Cp;
        u16* Qd = (u16*)ws;
        u16* K0 = (u16*)(ws + OFF_K0);
        u16* V0 = (u16*)(ws + OFF_V0); u16* V1 = (u16*)(ws + OFF_V1);
        u16* V2 = (u16*)(ws + OFF_V2); u16* V3 = (u16*)(ws + OFF_V3);
        const int region = n0 >> 10;
        if (region == 0) {             // ---- Q dense bf16 [tok][h*64+hd]
#pragma unroll
            for (int ti = 0; ti < 4; ti++)
#pragma unroll
                for (int tj = 0; tj < 4; tj++)
#pragma unroll
                    for (int r = 0; r < 4; r++) {
                        int m = m0 + wm * 64 + ti * 16 + quad * 4 + r;
                        int n = n0 + wn * 64 + tj * 16 + l15;
                        Qd[(size_t)m * 1024 + n] = f2bf(acc[ti][tj][r] + bias[n]);
                    }
        } else if (region == 1) {      // ---- K (only full-res copy), scale 0.125*log2(e)
#pragma unroll
            for (int ti = 0; ti < 4; ti++)
#pragma unroll
                for (int tj = 0; tj < 4; tj++) {
                    int n  = n0 + wn * 64 + tj * 16 + l15;
                    int nk = n - 1024;
                    int h = nk >> 6, hd = nk & 63;
#pragma unroll
                    for (int r = 0; r < 4; r++) {
                        int m = m0 + wm * 64 + ti * 16 + quad * 4 + r;
                        int bb = m >> 11, tok = m & 2047;
                        int bh = bb * 16 + h;
                        u16 bv = f2bf((acc[ti][tj][r] + bias[n]) * 0.18033688f);
                        K0[((size_t)bh * 2048 + tok) * 64 + hd] = bv;
                    }
                }
        } else {                       // ---- V^T dilated copies [b,h,hd,tok], permuted
#pragma unroll
            for (int ti = 0; ti < 4; ti++)
#pragma unroll
                for (int tj = 0; tj < 4; tj++) {
                    int n  = n0 + wn * 64 + tj * 16 + l15;
                    int nv = n - 2048;
                    int h = nv >> 6, hd = nv & 63;
                    int tokb = m0 + wm * 64 + ti * 16 + quad * 4;
                    int bb = tokb >> 11, tok = tokb & 2047;
                    int bh = bb * 16 + h;
                    float v0 = acc[ti][tj][0] + bias[n];
                    float v1 = acc[ti][tj][1] + bias[n];
                    float v2 = acc[ti][tj][2] + bias[n];
                    float v3 = acc[ti][tj][3] + bias[n];
                    u16 c0 = f2bf(v0), c1 = f2bf(v1), c2 = f2bf(v2), c3 = f2bf(v3);
                    uint2 pk;
                    pk.x = (uint32_t)c0 | ((uint32_t)c1 << 16);
                    pk.y = (uint32_t)c2 | ((uint32_t)c3 << 16);
                    // V0: swap bits 2<->3 of token index (tok%4==0, run of 4 intact)
                    int tokp = (tok & ~15) | ((tok & 4) << 1) | ((tok & 8) >> 1);
                    *(uint2*)&V0[((size_t)bh * 64 + hd) * 2048 + tokp] = pk;
                    // V1: kk=tok>>1 (even); pos = 8h+2g+u for kk=4g+2h+u
                    int kk = tok >> 1;
                    int v1p = (kk & ~15) | ((kk & 2) << 2) | ((kk & 12) >> 1);
                    *(uint32_t*)&V1[((size_t)bh * 64 + hd) * 1024 + v1p] =
                        (uint32_t)c0 | ((uint32_t)c2 << 16);
                    // V2: pos = 8h+4par+g for t = 8par+2g+h (t=tok>>2)
                    int t2 = tok >> 2;
                    int v2i = (t2 & ~15) | ((t2 & 1) << 3) | ((t2 & 15) >> 1);
                    V2[((size_t)bh * 64 + hd) * 512 + v2i] = c0;
                    // V3: natural order
                    if (!(quad & 1)) V3[((size_t)bh * 64 + hd) * 256 + (tok >> 3)] = c0;
                }
        }
    }
}

// exp + lane-local fragment packs for finished chunk (scores in sap, log2 domain)
#define EXPPACK(sap, phf)                                                      \
    {                                                                          \
        float e[16];                                                           \
        for (int g = 0; g < 4; g++) {                                          \
            float x0 = exp2f((sap)[g * 4 + 0]);                                \
            float x1 = exp2f((sap)[g * 4 + 1]);                                \
            float x2 = exp2f((sap)[g * 4 + 2]);                                \
            float x3 = exp2f((sap)[g * 4 + 3]);                                \
            e[g * 4 + 0] = x0; e[g * 4 + 1] = x1;                              \
            e[g * 4 + 2] = x2; e[g * 4 + 3] = x3;                              \
            ls0 += (x0 + x1) + (x2 + x3);                                      \
            ls1 += x0 + x2;                                                    \
            ls2 += x0;                                                         \
            if (!half) ls3 += x0;                                              \
        }                                                                      \
        F00 = pkt2(e[0],  e[1]);  F01 = pkt2(e[2],  e[3]);                     \
        F02 = pkt2(e[4],  e[5]);  F03 = pkt2(e[6],  e[7]);                     \
        F10 = pkt2(e[8],  e[9]);  F11 = pkt2(e[10], e[11]);                    \
        F12 = pkt2(e[12], e[13]); F13 = pkt2(e[14], e[15]);                    \
        G0  = pkt2(e[0],  e[2]);  G1  = pkt2(e[4],  e[6]);                     \
        G2  = pkt2(e[8],  e[10]); G3  = pkt2(e[12], e[14]);                    \
        Pa[(phf)] = pkt2(e[0], e[4]);                                          \
        Pb[(phf)] = pkt2(e[8], e[12]);                                         \
    }

// PV for finished chunk: scale0/1 every chunk; scale2 on odd chunks; scale3 on %4==3
#define PVALL(v0p, v1p, v2p, v3p, phf, DO2, DO3)                               \
    {                                                                          \
        uu p0; p0.u = (u32x4){F00, F01, F02, F03};                             \
        uu p1; p1.u = (u32x4){F10, F11, F12, F13};                             \
        for (int ht = 0; ht < 2; ht++) {                                       \
            bf8v va = *(const bf8v*)&(v0p)[(ht * 32 + l31) * 40 + half * 8];   \
            oacc0[ht] = __builtin_amdgcn_mfma_f32_32x32x16_bf16(va, p0.b, oacc0[ht], 0, 0, 0); \
            bf8v vb = *(const bf8v*)&(v0p)[(ht * 32 + l31) * 40 + 16 + half * 8]; \
            oacc0[ht] = __builtin_amdgcn_mfma_f32_32x32x16_bf16(vb, p1.b, oacc0[ht], 0, 0, 0); \
        }                                                                      \
        uu ps; ps.u = (u32x4){G0, G1, G2, G3};                                 \
        for (int ht = 0; ht < 2; ht++) {                                       \
            bf8v va1 = *(const bf8v*)&(v1p)[(ht * 32 + l31) * 24 + half * 8];  \
            oacc1[ht] = __builtin_amdgcn_mfma_f32_32x32x16_bf16(va1, ps.b, oacc1[ht], 0, 0, 0); \
        }                                                                      \
        if (DO2) {                                                             \
            uu p2; p2.u = (u32x4){Pa[((phf) + 3) & 3], Pb[((phf) + 3) & 3],    \
                                  Pa[(phf)], Pb[(phf)]};                       \
            for (int ht = 0; ht < 2; ht++) {                                   \
                bf8v va2 = *(const bf8v*)&(v2p)[(ht * 32 + l31) * 24 + half * 8]; \
                oacc2[ht] = __builtin_amdgcn_mfma_f32_32x32x16_bf16(va2, p2.b, oacc2[ht], 0, 0, 0); \
            }                                                                  \
        }                                                                      \
        if (DO3) {                                                             \
            uint32_t t0 = __shfl_xor(Pa[2], 32);                               \
            uint32_t t1 = __shfl_xor(Pb[2], 32);                               \
            uint32_t t2 = __shfl_xor(Pa[3], 32);                               \
            uint32_t t3 = __shfl_xor(Pb[3], 32);                               \
            uint32_t w0 = half ? t0 : Pa[0];                                   \
            uint32_t w1 = half ? t1 : Pb[0];                                   \
            uint32_t w2 = half ? t2 : Pa[1];                                   \
            uint32_t w3 = half ? t3 : Pb[1];                                   \
            uu p3; p3.u = (u32x4){w0, w1, w2, w3};                             \
            for (int ht = 0; ht < 2; ht++) {                                   \
                bf8v va3 = *(const bf8v*)&(v3p)[(ht * 32 + l31) * 24 + half * 8]; \
                oacc3[ht] = __builtin_amdgcn_mfma_f32_32x32x16_bf16(va3, p3.b, oacc3[ht], 0, 0, 0); \
            }                                                                  \
        }                                                                      \
    }

// ---------------- multi-scale attention: single K-pass, cross-chunk pipeline ----
// Iter i: [QK(i)] [exp/pack(i-1)] [LDS-stage chunk i+2] [loads chunk i+3]
//         [PV(i-1)] [barrier].  QK->exp dependency spans a barrier, so exp/PV
// always operate on retired scores. Buffer lifetimes: K written i-2 read i ->
// triple; V0/V1 written i-2 read i+1 -> quad; V2 triple; V3 double. 61.9KB LDS.
// XCD swizzle: the 16 q-tiles of one (b,h) share one XCD's L2 (~740KB set).
__global__ __launch_bounds__(256, 2) void attn_kernel(const char* __restrict__ ws) {
    __shared__ __align__(16) u16 smem[30976];
    auto KtB = [&](int i) { return smem + i * 2304; };           // [32][72] x3
    auto VtB = [&](int i) { return smem + 6912 + i * 2560; };    // [64][40] x4
    auto V1B = [&](int i) { return smem + 17152 + i * 1536; };   // [64][24] x4
    auto V2B = [&](int i) { return smem + 23296 + i * 1536; };   // [64][24] x3
    auto V3B = [&](int i) { return smem + 27904 + i * 1536; };   // [64][24] x2

    const u16* Qd    = (const u16*)(ws + OFF_Q);
    const float* scw = (const float*)(ws + OFF_SCW);
    u16* attnb       = (u16*)(ws + OFF_Q);          // aliases Q (block reads Q first)

    const int tid  = threadIdx.x;
    const int lane = tid & 63;
    const int wid  = tid >> 6;
    const int l31  = lane & 31;
    const int half = lane >> 5;

    // XCD-aware swizzle (bijective on 512 blocks): 4 (b,h) groups per XCD.
    const int f   = blockIdx.x + 16 * blockIdx.y + 256 * blockIdx.z;  // 0..511
    const int xcd = f & 7, jj = f >> 3;
    const int grp = xcd * 4 + (jj >> 4);    // 0..31 = (b,h)
    const int qt  = jj & 15;
    const int b = grp >> 4, h = grp & 15;
    const int q  = qt * 128 + wid * 32 + l31;
    const int bh = b * 16 + h;

    // cooperative staging coords (256 threads)
    const int skey = tid >> 3;             // 0..31
    const int shd8 = (tid & 7) * 8;
    const int svhd = tid >> 2;             // 0..63
    const int svk8 = (tid & 3) * 8;
    const int vi4  = (tid & 3) * 4;

    // Q B-frags: qf[ks] = Q[q][h*64 + ks*16 + half*8 + j]
    bf8v qf[4];
#pragma unroll
    for (int ks = 0; ks < 4; ks++)
        qf[ks] = *(const bf8v*)(Qd + (size_t)(b * SS + q) * 1024 + h * 64 + ks * 16 + half * 8);

    const u16* Kb  = (const u16*)(ws + OFF_K0) + (size_t)bh * (2048 * 64);
    const u16* Vb0 = (const u16*)(ws + OFF_V0) + (size_t)bh * (64 * 2048);
    const u16* Vb1 = (const u16*)(ws + OFF_V1) + (size_t)bh * (64 * 1024);
    const u16* Vb2 = (const u16*)(ws + OFF_V2) + (size_t)bh * (64 * 512);
    const u16* Vb3 = (const u16*)(ws + OFF_V3) + (size_t)bh * (64 * 256);

    f16v oacc0[2], oacc1[2], oacc2[2], oacc3[2];
#pragma unroll
    for (int ht = 0; ht < 2; ht++)
#pragma unroll
        for (int r = 0; r < 16; r++) {
            oacc0[ht][r] = 0.f; oacc1[ht][r] = 0.f;
            oacc2[ht][r] = 0.f; oacc3[ht][r] = 0.f;
        }
    float ls0 = 0.f, ls1 = 0.f, ls2 = 0.f, ls3 = 0.f;

    // ---- prologue: direct-stage chunks 0,1 (K,V0,V1) + V2 g0 + V3 g0;
    //      preload regs for chunk 2 (+ V2 group 2)
#pragma unroll
    for (int cN = 0; cN < 2; cN++) {
        *(uint4*)&KtB(cN)[skey * 72 + shd8] =
            *(const uint4*)(Kb + (size_t)(cN * 32 + skey) * 64 + shd8);
        *(uint4*)&VtB(cN)[svhd * 40 + svk8] =
            *(const uint4*)(Vb0 + (size_t)svhd * 2048 + cN * 32 + svk8);
        *(uint2*)&V1B(cN)[svhd * 24 + vi4] =
            *(const uint2*)(Vb1 + (size_t)svhd * 1024 + cN * 16 + vi4);
    }
    *(uint2*)&V2B(0)[svhd * 24 + vi4] = *(const uint2*)(Vb2 + (size_t)svhd * 512 + vi4);
    *(uint2*)&V3B(0)[svhd * 24 + vi4] = *(const uint2*)(Vb3 + (size_t)svhd * 256 + vi4);
    uint4 kr  = *(const uint4*)(Kb  + (size_t)(64 + skey) * 64 + shd8);
    uint4 vr  = *(const uint4*)(Vb0 + (size_t)svhd * 2048 + 64 + svk8);
    uint2 v1r = *(const uint2*)(Vb1 + (size_t)svhd * 1024 + 32 + vi4);
    uint2 v2r = *(const uint2*)(Vb2 + (size_t)svhd * 512 + 16 + vi4);
    uint2 v3r = {};
    __syncthreads();

    uint32_t Pa[4], Pb[4];
    f16v sa0, sa1;
    union uu { u32x4 u; bf8v b; };

    for (int cc = 0; cc < 64; cc += 4) {
#pragma unroll
        for (int ph = 0; ph < 4; ph++) {
            const int c = cc + ph;
            const int phf = (ph + 3) & 3;            // finished chunk's phase
            const bool dofin = (ph > 0) || (cc > 0);
            uint32_t F00, F01, F02, F03, F10, F11, F12, F13, G0, G1, G2, G3;

            // ---- QK(c): S^T col=q(l31), rows=key (log2 domain)
            f16v& sc = (ph & 1) ? sa1 : sa0;
            const f16v& sp = (ph & 1) ? sa0 : sa1;
#pragma unroll
            for (int r = 0; r < 16; r++) sc[r] = 0.f;
            {
                u16* kt = KtB(c % 3);
#pragma unroll
                for (int ks = 0; ks < 4; ks++) {
                    bf8v ka = *(const bf8v*)&kt[l31 * 72 + ks * 16 + half * 8];
                    sc = __builtin_amdgcn_mfma_f32_32x32x16_bf16(ka, qf[ks], sc, 0, 0, 0);
                }
            }
            // ---- finish chunk c-1: exp2 + packs (scores retired last iter)
            if (dofin) EXPPACK(sp, phf)
            // ---- LDS-stage chunk c+2 (regs loaded at iter c-1)
            if (c + 2 < 64) {
                *(uint4*)&KtB((c + 2) % 3)[skey * 72 + shd8] = kr;
                *(uint4*)&VtB((ph + 2) & 3)[svhd * 40 + svk8] = vr;
                *(uint2*)&V1B((ph + 2) & 3)[svhd * 24 + vi4] = v1r;
                if (((c + 2) & 1) == 0) {
                    *(uint2*)&V2B(((c + 2) >> 1) % 3)[svhd * 24 + vi4] = v2r;
                    if (((c + 2) & 3) == 0)
                        *(uint2*)&V3B(((c + 2) >> 2) & 1)[svhd * 24 + vi4] = v3r;
                }
            }
            // ---- global loads for chunk c+3
            if (c + 3 < 64) {
                kr  = *(const uint4*)(Kb  + (size_t)((c + 3) * 32 + skey) * 64 + shd8);
                vr  = *(const uint4*)(Vb0 + (size_t)svhd * 2048 + (c + 3) * 32 + svk8);
                v1r = *(const uint2*)(Vb1 + (size_t)svhd * 1024 + (c + 3) * 16 + vi4);
                if (((c + 3) & 1) == 0) {
                    v2r = *(const uint2*)(Vb2 + (size_t)svhd * 512 + (c + 3) * 8 + vi4);
                    if (((c + 3) & 3) == 0)
                        v3r = *(const uint2*)(Vb3 + (size_t)svhd * 256 + (c + 3) * 4 + vi4);
                }
            }
            // ---- PV for chunk c-1
            if (dofin)
                PVALL(VtB((ph + 3) & 3), V1B((ph + 3) & 3),
                      V2B(((c - 2) >> 1) % 3), V3B(((c - 4) >> 2) & 1),
                      phf, (phf == 1 || phf == 3), (phf == 3))
            __syncthreads();
        }
    }
    // ---- epilogue: finish chunk 63 (phase 3; V2 pair g=62 -> buf 1; V3 G=60 -> buf 1)
    {
        const f16v& sp = sa1;
        uint32_t F00, F01, F02, F03, F10, F11, F12, F13, G0, G1, G2, G3;
        EXPPACK(sp, 3)
        PVALL(VtB(3), V1B(3), V2B(1), V3B(1), 3, true, true)
    }
    // ---- fold the 4 scales: ofin = sum_s (w_s / ls_s) * oacc_s
    ls0 += __shfl_xor(ls0, 32);
    ls1 += __shfl_xor(ls1, 32);
    ls2 += __shfl_xor(ls2, 32);
    ls3 += __shfl_xor(ls3, 32);
    float4 sw = *(const float4*)&scw[(size_t)(b * SS + q) * 4];
    float w0 = sw.x / ls0, w1 = sw.y / ls1, w2 = sw.z / ls2, w3 = sw.w / ls3;

    const size_t base = (size_t)(b * SS + q) * 1024 + h * 64;
#pragma unroll
    for (int ht = 0; ht < 2; ht++)
#pragma unroll
        for (int g = 0; g < 4; g++) {
            float f0 = w0 * oacc0[ht][g * 4 + 0] + w1 * oacc1[ht][g * 4 + 0]
                     + w2 * oacc2[ht][g * 4 + 0] + w3 * oacc3[ht][g * 4 + 0];
            float f1 = w0 * oacc0[ht][g * 4 + 1] + w1 * oacc1[ht][g * 4 + 1]
                     + w2 * oacc2[ht][g * 4 + 1] + w3 * oacc3[ht][g * 4 + 1];
            float f2 = w0 * oacc0[ht][g * 4 + 2] + w1 * oacc1[ht][g * 4 + 2]
                     + w2 * oacc2[ht][g * 4 + 2] + w3 * oacc3[ht][g * 4 + 2];
            float f3 = w0 * oacc0[ht][g * 4 + 3] + w1 * oacc1[ht][g * 4 + 3]
                     + w2 * oacc2[ht][g * 4 + 3] + w3 * oacc3[ht][g * 4 + 3];
            uint2 pk;
            pk.x = pk2(f0, f1);
            pk.y = pk2(f2, f3);
            *(uint2*)&attnb[base + ht * 32 + g * 8 + half * 4] = pk;
        }
}

extern "C" void kernel_launch(void* const* d_in, const int* in_sizes, int n_in,
                              void* d_out, int out_size, void* d_ws, size_t ws_size,
                              hipStream_t stream) {
    const float* x      = (const float*)d_in[0];
    const float* Wqkv   = (const float*)d_in[1];
    const float* bqkv   = (const float*)d_in[2];
    const float* Wout   = (const float*)d_in[3];
    const float* bout   = (const float*)d_in[4];
    const float* Wscale = (const float*)d_in[5];
    const float* bscale = (const float*)d_in[6];
    float* out = (float*)d_out;

    char* ws = (char*)d_ws;
    u16*   wqt   = (u16*)(ws + OFF_WQT);
    u16*   wot   = (u16*)(ws + OFF_WOT);
    u16*   xb    = (u16*)(ws + OFF_XB);
    u16*   attnb = (u16*)(ws + OFF_Q);
    float* scw   = (float*)(ws + OFF_SCW);

    xconv_kernel<<<dim3(4096), dim3(256), 0, stream>>>(x, xb);
    wconv_kernel<<<dim3(48, 16), dim3(256), 0, stream>>>(Wqkv, wqt, 3072, 1024);
    wconv_kernel<<<dim3(16, 16), dim3(256), 0, stream>>>(Wout, wot, 1024, 1024);
    scale_kernel<<<dim3(1024), dim3(256), 0, stream>>>(x, Wscale, bscale, scw);
    gemm_bt<1><<<dim3(24, 32), dim3(256), 0, stream>>>(xb, wqt, bqkv, (void*)ws, 3072, 1024);
    attn_kernel<<<dim3(16, 16, 2), dim3(256), 0, stream>>>(ws);
    gemm_bt<0><<<dim3(8, 32), dim3(256), 0, stream>>>(attnb, wot, bout, (void*)out, 1024, 1024);
}

// Round 5
// 298.782 us; speedup vs baseline: 1.0458x; 1.0458x over previous
//
#include <hip/hip_runtime.h>
#include <stdint.h>

typedef unsigned short u16;
typedef __attribute__((ext_vector_type(8))) __bf16 bf8v;    // A/B fragment: 8 bf16
typedef __attribute__((ext_vector_type(4))) float f4v;      // 16x16 C/D
typedef __attribute__((ext_vector_type(16))) float f16v;    // 32x32 C/D
typedef __attribute__((ext_vector_type(4))) uint32_t u32x4;

#define BB 2
#define SS 2048
#define HH 1024

// workspace layout (bytes) — extent 56688640.
#define OFF_Q   0u          // Q bf16 [4096][1024]; later attn output (same region)
#define OFF_K0  8388608u
#define OFF_V0  24117248u
#define OFF_V1  32505856u
#define OFF_V2  36700160u
#define OFF_V3  38797312u
#define OFF_WQT 39845888u   // Wqkv^T bf16 [3072][1024]  (6 MB)
#define OFF_WOT 46137344u   // Wout^T bf16 [1024][1024]  (2 MB)
#define OFF_XB  48234496u   // x bf16 [4096][1024]       (8 MB)
#define OFF_SCW 56623104u   // scale weights f32 [4096][4] (64 KB)

__device__ __forceinline__ u16 f2bf(float f) {
    union { float f; uint32_t u; } v; v.f = f;
    uint32_t r = v.u + 0x7fffu + ((v.u >> 16) & 1u);   // RNE
    return (u16)(r >> 16);
}
__device__ __forceinline__ uint32_t pk2(float a, float b) {
    return (uint32_t)f2bf(a) | ((uint32_t)f2bf(b) << 16);
}
// truncation pack (2 VALU): low half <- bf-trunc(a), high half <- bf-trunc(b)
__device__ __forceinline__ uint32_t pkt2(float a, float b) {
    union { float f; uint32_t u; } x, y; x.f = a; y.f = b;
    return (x.u >> 16) | (y.u & 0xffff0000u);
}

// ---------------- x f32 -> bf16 ----------------
__global__ __launch_bounds__(256) void xconv_kernel(const float* __restrict__ x,
                                                    u16* __restrict__ xb) {
    size_t t = (size_t)blockIdx.x * 256 + threadIdx.x;
    float4 v = *(const float4*)&x[t * 4];
    uint2 pk; pk.x = pk2(v.x, v.y); pk.y = pk2(v.z, v.w);
    *(uint2*)&xb[t * 4] = pk;
}

// ---------------- W f32 [K][N] -> bf16 W^T [N][K] ----------------
__global__ __launch_bounds__(256) void wconv_kernel(const float* __restrict__ W,
                                                    u16* __restrict__ Wt,
                                                    int N, int K) {
    __shared__ float tile[64][69];
    const int tid = threadIdx.x;
    const int n0 = blockIdx.x * 64, k0 = blockIdx.y * 64;
    const int r = tid >> 4, c4 = (tid & 15) * 4;
#pragma unroll
    for (int it = 0; it < 4; it++) {
        float4 v = *(const float4*)&W[(size_t)(k0 + it * 16 + r) * N + n0 + c4];
        tile[it * 16 + r][c4 + 0] = v.x; tile[it * 16 + r][c4 + 1] = v.y;
        tile[it * 16 + r][c4 + 2] = v.z; tile[it * 16 + r][c4 + 3] = v.w;
    }
    __syncthreads();
#pragma unroll
    for (int it = 0; it < 4; it++) {
        int n = it * 16 + r;
        uint2 pk;
        pk.x = pk2(tile[c4 + 0][n], tile[c4 + 1][n]);
        pk.y = pk2(tile[c4 + 2][n], tile[c4 + 3][n]);
        *(uint2*)&Wt[(size_t)(n0 + n) * K + k0 + c4] = pk;
    }
}

// ---------------- scale weights: softmax(x @ Wscale + bscale) ----------------
__global__ __launch_bounds__(256) void scale_kernel(const float* __restrict__ x,
                                                    const float* __restrict__ Wscale,
                                                    const float* __restrict__ bscale,
                                                    float* __restrict__ scw) {
    const int lane = threadIdx.x & 63;
    const int wid  = threadIdx.x >> 6;
    const int row  = blockIdx.x * 4 + wid;
    float a0 = 0.f, a1 = 0.f, a2 = 0.f, a3 = 0.f;
    for (int i = 0; i < 16; i++) {
        int hh = lane + i * 64;
        float xs = x[(size_t)row * HH + hh];
        float4 wv = *(const float4*)&Wscale[hh * 4];
        a0 += xs * wv.x; a1 += xs * wv.y; a2 += xs * wv.z; a3 += xs * wv.w;
    }
    for (int off = 1; off < 64; off <<= 1) {
        a0 += __shfl_xor(a0, off); a1 += __shfl_xor(a1, off);
        a2 += __shfl_xor(a2, off); a3 += __shfl_xor(a3, off);
    }
    if (lane == 0) {
        a0 += bscale[0]; a1 += bscale[1]; a2 += bscale[2]; a3 += bscale[3];
        float mx = fmaxf(fmaxf(a0, a1), fmaxf(a2, a3));
        float e0 = __expf(a0 - mx), e1 = __expf(a1 - mx);
        float e2 = __expf(a2 - mx), e3 = __expf(a3 - mx);
        float inv = 1.f / (e0 + e1 + e2 + e3);
        float4 o = {e0 * inv, e1 * inv, e2 * inv, e3 * inv};
        *(float4*)&scw[(size_t)row * 4] = o;
    }
}

// ---------------- bf16 MFMA GEMM, A bf16, B pre-transposed bf16 ----------------
// MODE 0: C[M,N] f32 = A@B + bias.  MODE 1: QKV scatter epilogue.
// K scaled by 1/sqrt(64) * log2(e) so attn can use exp2 directly.
// V0/V1/V2 stored KEY-PERMUTED (within 16-blocks) so attn PV B-fragments are
// lane-local (permuting the MFMA contraction index identically on both
// operands leaves the product unchanged).
template<int MODE>
__global__ __launch_bounds__(256) void gemm_bt(const u16* __restrict__ A,
                                               const u16* __restrict__ Bt,
                                               const float* __restrict__ bias,
                                               void* __restrict__ Cp,
                                               int N, int K) {
    __shared__ __align__(16) u16 At[128 * 40];
    __shared__ __align__(16) u16 Btl[128 * 40];
    const int tid  = threadIdx.x;
    const int lane = tid & 63;
    const int wid  = tid >> 6;
    const int l15  = lane & 15;
    const int quad = lane >> 4;
    const int wm = wid & 1, wn = wid >> 1;
    const int m0 = blockIdx.y * 128;
    const int n0 = blockIdx.x * 128;
    const int srow = tid >> 2;           // 0..63
    const int sc8  = (tid & 3) * 8;      // 0,8,16,24

    f4v acc[4][4];
#pragma unroll
    for (int i = 0; i < 4; i++)
#pragma unroll
        for (int j = 0; j < 4; j++) acc[i][j] = (f4v){0.f, 0.f, 0.f, 0.f};

    uint4 pa0 = *(const uint4*)(A  + (size_t)(m0 + srow) * K + sc8);
    uint4 pa1 = *(const uint4*)(A  + (size_t)(m0 + srow + 64) * K + sc8);
    uint4 pb0 = *(const uint4*)(Bt + (size_t)(n0 + srow) * K + sc8);
    uint4 pb1 = *(const uint4*)(Bt + (size_t)(n0 + srow + 64) * K + sc8);

    for (int kc = 0; kc < K; kc += 32) {
        __syncthreads();
        *(uint4*)&At[srow * 40 + sc8]         = pa0;
        *(uint4*)&At[(srow + 64) * 40 + sc8]  = pa1;
        *(uint4*)&Btl[srow * 40 + sc8]        = pb0;
        *(uint4*)&Btl[(srow + 64) * 40 + sc8] = pb1;
        __syncthreads();
        if (kc + 32 < K) {
            pa0 = *(const uint4*)(A  + (size_t)(m0 + srow) * K + kc + 32 + sc8);
            pa1 = *(const uint4*)(A  + (size_t)(m0 + srow + 64) * K + kc + 32 + sc8);
            pb0 = *(const uint4*)(Bt + (size_t)(n0 + srow) * K + kc + 32 + sc8);
            pb1 = *(const uint4*)(Bt + (size_t)(n0 + srow + 64) * K + kc + 32 + sc8);
        }
        bf8v af[4], bf[4];
#pragma unroll
        for (int t = 0; t < 4; t++) {
            af[t] = *(const bf8v*)&At[(wm * 64 + t * 16 + l15) * 40 + quad * 8];
            bf[t] = *(const bf8v*)&Btl[(wn * 64 + t * 16 + l15) * 40 + quad * 8];
        }
#pragma unroll
        for (int ti = 0; ti < 4; ti++)
#pragma unroll
            for (int tj = 0; tj < 4; tj++)
                acc[ti][tj] = __builtin_amdgcn_mfma_f32_16x16x32_bf16(af[ti], bf[tj], acc[ti][tj], 0, 0, 0);
    }

    if (MODE == 0) {
#pragma unroll
        for (int ti = 0; ti < 4; ti++)
#pragma unroll
            for (int tj = 0; tj < 4; tj++)
#pragma unroll
                for (int r = 0; r < 4; r++) {
                    int m = m0 + wm * 64 + ti * 16 + quad * 4 + r;
                    int n = n0 + wn * 64 + tj * 16 + l15;
                    ((float*)Cp)[(size_t)m * N + n] = acc[ti][tj][r] + bias[n];
                }
    } else {
        char* ws = (char*)Cp;
        u16* Qd = (u16*)ws;
        u16* K0 = (u16*)(ws + OFF_K0);
        u16* V0 = (u16*)(ws + OFF_V0); u16* V1 = (u16*)(ws + OFF_V1);
        u16* V2 = (u16*)(ws + OFF_V2); u16* V3 = (u16*)(ws + OFF_V3);
        const int region = n0 >> 10;
        if (region == 0) {             // ---- Q dense bf16 [tok][h*64+hd]
#pragma unroll
            for (int ti = 0; ti < 4; ti++)
#pragma unroll
                for (int tj = 0; tj < 4; tj++)
#pragma unroll
                    for (int r = 0; r < 4; r++) {
                        int m = m0 + wm * 64 + ti * 16 + quad * 4 + r;
                        int n = n0 + wn * 64 + tj * 16 + l15;
                        Qd[(size_t)m * 1024 + n] = f2bf(acc[ti][tj][r] + bias[n]);
                    }
        } else if (region == 1) {      // ---- K (only full-res copy), scale 0.125*log2(e)
#pragma unroll
            for (int ti = 0; ti < 4; ti++)
#pragma unroll
                for (int tj = 0; tj < 4; tj++) {
                    int n  = n0 + wn * 64 + tj * 16 + l15;
                    int nk = n - 1024;
                    int h = nk >> 6, hd = nk & 63;
#pragma unroll
                    for (int r = 0; r < 4; r++) {
                        int m = m0 + wm * 64 + ti * 16 + quad * 4 + r;
                        int bb = m >> 11, tok = m & 2047;
                        int bh = bb * 16 + h;
                        u16 bv = f2bf((acc[ti][tj][r] + bias[n]) * 0.18033688f);
                        K0[((size_t)bh * 2048 + tok) * 64 + hd] = bv;
                    }
                }
        } else {                       // ---- V^T dilated copies [b,h,hd,tok], permuted
#pragma unroll
            for (int ti = 0; ti < 4; ti++)
#pragma unroll
                for (int tj = 0; tj < 4; tj++) {
                    int n  = n0 + wn * 64 + tj * 16 + l15;
                    int nv = n - 2048;
                    int h = nv >> 6, hd = nv & 63;
                    int tokb = m0 + wm * 64 + ti * 16 + quad * 4;
                    int bb = tokb >> 11, tok = tokb & 2047;
                    int bh = bb * 16 + h;
                    float v0 = acc[ti][tj][0] + bias[n];
                    float v1 = acc[ti][tj][1] + bias[n];
                    float v2 = acc[ti][tj][2] + bias[n];
                    float v3 = acc[ti][tj][3] + bias[n];
                    u16 c0 = f2bf(v0), c1 = f2bf(v1), c2 = f2bf(v2), c3 = f2bf(v3);
                    uint2 pk;
                    pk.x = (uint32_t)c0 | ((uint32_t)c1 << 16);
                    pk.y = (uint32_t)c2 | ((uint32_t)c3 << 16);
                    // V0: swap bits 2<->3 of token index (tok%4==0, run of 4 intact)
                    int tokp = (tok & ~15) | ((tok & 4) << 1) | ((tok & 8) >> 1);
                    *(uint2*)&V0[((size_t)bh * 64 + hd) * 2048 + tokp] = pk;
                    // V1: kk=tok>>1 (even); pos = 8h+2g+u for kk=4g+2h+u
                    int kk = tok >> 1;
                    int v1p = (kk & ~15) | ((kk & 2) << 2) | ((kk & 12) >> 1);
                    *(uint32_t*)&V1[((size_t)bh * 64 + hd) * 1024 + v1p] =
                        (uint32_t)c0 | ((uint32_t)c2 << 16);
                    // V2: pos = 8h+4par+g for t = 8par+2g+h (t=tok>>2)
                    int t2 = tok >> 2;
                    int v2i = (t2 & ~15) | ((t2 & 1) << 3) | ((t2 & 15) >> 1);
                    V2[((size_t)bh * 64 + hd) * 512 + v2i] = c0;
                    // V3: natural order
                    if (!(quad & 1)) V3[((size_t)bh * 64 + hd) * 256 + (tok >> 3)] = c0;
                }
        }
    }
}

// per-g exp + packs (log2-domain scores)
#define EPG(sav, g, Fa, Fb, Gg, xout)                                        \
    { float x0 = exp2f((sav)[4*(g)+0]); float x1 = exp2f((sav)[4*(g)+1]);    \
      float x2 = exp2f((sav)[4*(g)+2]); float x3 = exp2f((sav)[4*(g)+3]);    \
      ls0 += (x0 + x1) + (x2 + x3); ls1 += x0 + x2; ls2 += x0;               \
      if (!half) ls3 += x0;                                                  \
      Fa = pkt2(x0, x1); Fb = pkt2(x2, x3); Gg = pkt2(x0, x2); xout = x0; }

#define EPACK(sav, Pp, Pq)                                                   \
    { float y0, y1, y2, y3;                                                  \
      EPG(sav, 0, F0, F1, G0, y0) EPG(sav, 1, F2, F3, G1, y1)                \
      EPG(sav, 2, F4, F5, G2, y2) EPG(sav, 3, F6, F7, G3, y3)                \
      Pp = pkt2(y0, y1); Pq = pkt2(y2, y3); }

// PV scale0 (2 MFMAs x 2 ht) + scale1 (1 x 2 ht) for one 32-key sub-chunk
#define PV01(JP, V0OFF, V1OFF)                                               \
    { uu p0; p0.u = (u32x4){F0, F1, F2, F3};                                 \
      uu p1; p1.u = (u32x4){F4, F5, F6, F7};                                 \
      uu ps; ps.u = (u32x4){G0, G1, G2, G3};                                 \
      u16* v0p = V0B(JP); u16* v1p = V1B(JP);                                \
      bf8v va0 = *(const bf8v*)&v0p[(l31) * 72 + (V0OFF) + half * 8];        \
      oacc0[0] = __builtin_amdgcn_mfma_f32_32x32x16_bf16(va0, p0.b, oacc0[0], 0, 0, 0); \
      bf8v vb0 = *(const bf8v*)&v0p[(l31) * 72 + (V0OFF) + 16 + half * 8];   \
      oacc0[0] = __builtin_amdgcn_mfma_f32_32x32x16_bf16(vb0, p1.b, oacc0[0], 0, 0, 0); \
      bf8v va1 = *(const bf8v*)&v0p[(32 + l31) * 72 + (V0OFF) + half * 8];   \
      oacc0[1] = __builtin_amdgcn_mfma_f32_32x32x16_bf16(va1, p0.b, oacc0[1], 0, 0, 0); \
      bf8v vb1 = *(const bf8v*)&v0p[(32 + l31) * 72 + (V0OFF) + 16 + half * 8]; \
      oacc0[1] = __builtin_amdgcn_mfma_f32_32x32x16_bf16(vb1, p1.b, oacc0[1], 0, 0, 0); \
      bf8v vc0 = *(const bf8v*)&v1p[(l31) * 40 + (V1OFF) + half * 8];        \
      oacc1[0] = __builtin_amdgcn_mfma_f32_32x32x16_bf16(vc0, ps.b, oacc1[0], 0, 0, 0); \
      bf8v vc1 = *(const bf8v*)&v1p[(32 + l31) * 40 + (V1OFF) + half * 8];   \
      oacc1[1] = __builtin_amdgcn_mfma_f32_32x32x16_bf16(vc1, ps.b, oacc1[1], 0, 0, 0); }

// one 64-key iteration, JP = j&1 (static)
#define AITER(JP)                                                            \
    { const int j = jj + (JP);                                               \
      u16* kt = KtB(JP);                                                     \
      f16v saA = {0,0,0,0,0,0,0,0,0,0,0,0,0,0,0,0};                          \
      f16v saB = {0,0,0,0,0,0,0,0,0,0,0,0,0,0,0,0};                          \
      bf8v ka0A = *(const bf8v*)&kt[l31 * 72 + 0 * 16 + half * 8];           \
      bf8v ka0B = *(const bf8v*)&kt[(32 + l31) * 72 + 0 * 16 + half * 8];    \
      bf8v ka1A = *(const bf8v*)&kt[l31 * 72 + 1 * 16 + half * 8];           \
      bf8v ka1B = *(const bf8v*)&kt[(32 + l31) * 72 + 1 * 16 + half * 8];    \
      bf8v ka2A = *(const bf8v*)&kt[l31 * 72 + 2 * 16 + half * 8];           \
      bf8v ka2B = *(const bf8v*)&kt[(32 + l31) * 72 + 2 * 16 + half * 8];    \
      bf8v ka3A = *(const bf8v*)&kt[l31 * 72 + 3 * 16 + half * 8];           \
      bf8v ka3B = *(const bf8v*)&kt[(32 + l31) * 72 + 3 * 16 + half * 8];    \
      saA = __builtin_amdgcn_mfma_f32_32x32x16_bf16(ka0A, qf[0], saA, 0, 0, 0); \
      saB = __builtin_amdgcn_mfma_f32_32x32x16_bf16(ka0B, qf[0], saB, 0, 0, 0); \
      saA = __builtin_amdgcn_mfma_f32_32x32x16_bf16(ka1A, qf[1], saA, 0, 0, 0); \
      saB = __builtin_amdgcn_mfma_f32_32x32x16_bf16(ka1B, qf[1], saB, 0, 0, 0); \
      saA = __builtin_amdgcn_mfma_f32_32x32x16_bf16(ka2A, qf[2], saA, 0, 0, 0); \
      saB = __builtin_amdgcn_mfma_f32_32x32x16_bf16(ka2B, qf[2], saB, 0, 0, 0); \
      saA = __builtin_amdgcn_mfma_f32_32x32x16_bf16(ka3A, qf[3], saA, 0, 0, 0); \
      saB = __builtin_amdgcn_mfma_f32_32x32x16_bf16(ka3B, qf[3], saB, 0, 0, 0); \
      /* stage chunk j+1 from regs (loaded last iter) */                     \
      if (j + 1 < 32) {                                                      \
          u16* ktn = KtB(1 - (JP));                                          \
          *(uint4*)&ktn[sr * 72 + sc8]          = kr0;                       \
          *(uint4*)&ktn[sr * 72 + 32 + sc8]     = kr1;                       \
          u16* v0n = V0B(1 - (JP));                                          \
          *(uint4*)&v0n[sr * 72 + sc8]          = vr0;                       \
          *(uint4*)&v0n[sr * 72 + 32 + sc8]     = vr1;                       \
          *(uint4*)&V1B(1 - (JP))[sr * 40 + sc8] = v1r;                      \
          *(uint2*)&V2B(1 - (JP))[sr * 24 + vi4] = v2r;                      \
          if ((JP) == 1)                                                     \
              *(uint2*)&V3B(((j + 1) >> 1) & 1)[sr * 24 + vi4] = v3r;        \
      }                                                                      \
      /* global prefetch chunk j+2 */                                        \
      if (j + 2 < 32) {                                                      \
          kr0 = *(const uint4*)(Kb  + (size_t)((j + 2) * 64 + sr) * 64 + sc8);       \
          kr1 = *(const uint4*)(Kb  + (size_t)((j + 2) * 64 + sr) * 64 + 32 + sc8);  \
          vr0 = *(const uint4*)(Vb0 + (size_t)sr * 2048 + (j + 2) * 64 + sc8);       \
          vr1 = *(const uint4*)(Vb0 + (size_t)sr * 2048 + (j + 2) * 64 + 32 + sc8);  \
          v1r = *(const uint4*)(Vb1 + (size_t)sr * 1024 + (j + 2) * 32 + sc8);       \
          v2r = *(const uint2*)(Vb2 + (size_t)sr * 512 + (j + 2) * 16 + vi4);        \
      }                                                                      \
      if ((JP) == 0 && (j >> 1) + 1 < 16)                                    \
          v3r = *(const uint2*)(Vb3 + (size_t)sr * 256 + ((j >> 1) + 1) * 16 + vi4); \
      /* sub A: exp+pack, PV s0/s1 */                                        \
      uint32_t F0, F1, F2, F3, F4, F5, F6, F7, G0, G1, G2, G3;               \
      uint32_t PaA, PbA, PaB, PbB;                                           \
      EPACK(saA, PaA, PbA)                                                   \
      PV01(JP, 0, 0)                                                         \
      /* sub B: exp+pack, PV s0/s1 */                                        \
      EPACK(saB, PaB, PbB)                                                   \
      PV01(JP, 32, 16)                                                       \
      /* scale 2: all 16 %4-keys of this chunk (V2 key-permuted) */          \
      { uu p2; p2.u = (u32x4){PaA, PbA, PaB, PbB};                           \
        u16* v2p = V2B(JP);                                                  \
        bf8v w0 = *(const bf8v*)&v2p[l31 * 24 + half * 8];                   \
        oacc2[0] = __builtin_amdgcn_mfma_f32_32x32x16_bf16(w0, p2.b, oacc2[0], 0, 0, 0); \
        bf8v w1 = *(const bf8v*)&v2p[(32 + l31) * 24 + half * 8];            \
        oacc2[1] = __builtin_amdgcn_mfma_f32_32x32x16_bf16(w1, p2.b, oacc2[1], 0, 0, 0); } \
      /* scale 3: odd iters, group (j>>1); half0 words from prev iter */     \
      if ((JP) == 1) {                                                       \
          uint32_t s0 = __shfl_xor(PaA, 32), s1 = __shfl_xor(PbA, 32);       \
          uint32_t s2 = __shfl_xor(PaB, 32), s3 = __shfl_xor(PbB, 32);       \
          uint32_t w0 = half ? s0 : cPaA, w1 = half ? s1 : cPbA;             \
          uint32_t w2 = half ? s2 : cPaB, w3 = half ? s3 : cPbB;             \
          uu p3; p3.u = (u32x4){w0, w1, w2, w3};                             \
          u16* v3p = V3B((j >> 1) & 1);                                      \
          bf8v y0 = *(const bf8v*)&v3p[l31 * 24 + half * 8];                 \
          oacc3[0] = __builtin_amdgcn_mfma_f32_32x32x16_bf16(y0, p3.b, oacc3[0], 0, 0, 0); \
          bf8v y1 = *(const bf8v*)&v3p[(32 + l31) * 24 + half * 8];          \
          oacc3[1] = __builtin_amdgcn_mfma_f32_32x32x16_bf16(y1, p3.b, oacc3[1], 0, 0, 0); \
      } else { cPaA = PaA; cPbA = PbA; cPaB = PaB; cPbB = PbB; }             \
      __syncthreads(); }

// ---------------- multi-scale attention: single K-pass, 64-key chunks ----------
// 32 iterations of 64 keys: two independent QK chains/iter (MFMA latency hidden),
// half the barriers of r3, double the prefetch->use distance. All P fragments
// lane-local (V0/V1/V2 key-permuted in GEMM epilogue); scale3 carries 4 u32
// across one iteration. LDS 59.4 KB double-buffered; no cross-barrier score state.
__global__ __launch_bounds__(256, 2) void attn_kernel(const char* __restrict__ ws) {
    __shared__ __align__(16) u16 smem[29696];
    auto KtB = [&](int i) { return smem + i * 4608; };           // [64][72] x2
    auto V0B = [&](int i) { return smem + 9216 + i * 4608; };    // [64][72] x2
    auto V1B = [&](int i) { return smem + 18432 + i * 2560; };   // [64][40] x2
    auto V2B = [&](int i) { return smem + 23552 + i * 1536; };   // [64][24] x2
    auto V3B = [&](int i) { return smem + 26624 + i * 1536; };   // [64][24] x2

    const u16* Qd    = (const u16*)(ws + OFF_Q);
    const float* scw = (const float*)(ws + OFF_SCW);
    u16* attnb       = (u16*)(ws + OFF_Q);          // aliases Q (block reads Q first)

    const int tid  = threadIdx.x;
    const int lane = tid & 63;
    const int wid  = tid >> 6;
    const int l31  = lane & 31;
    const int half = lane >> 5;

    // XCD-aware swizzle (bijective on 512 blocks): 4 (b,h) groups per XCD.
    const int f   = blockIdx.x + 16 * blockIdx.y + 256 * blockIdx.z;  // 0..511
    const int xcd = f & 7, jj2 = f >> 3;
    const int grp = xcd * 4 + (jj2 >> 4);    // 0..31 = (b,h)
    const int qt  = jj2 & 15;
    const int b = grp >> 4, h = grp & 15;
    const int q  = qt * 128 + wid * 32 + l31;
    const int bh = b * 16 + h;

    // cooperative staging coords (256 threads): row sr, col blocks
    const int sr  = tid >> 2;              // 0..63
    const int sc8 = (tid & 3) * 8;         // 0,8,16,24
    const int vi4 = (tid & 3) * 4;

    // Q B-frags: qf[ks] = Q[q][h*64 + ks*16 + half*8 + j]
    bf8v qf[4];
#pragma unroll
    for (int ks = 0; ks < 4; ks++)
        qf[ks] = *(const bf8v*)(Qd + (size_t)(b * SS + q) * 1024 + h * 64 + ks * 16 + half * 8);

    const u16* Kb  = (const u16*)(ws + OFF_K0) + (size_t)bh * (2048 * 64);
    const u16* Vb0 = (const u16*)(ws + OFF_V0) + (size_t)bh * (64 * 2048);
    const u16* Vb1 = (const u16*)(ws + OFF_V1) + (size_t)bh * (64 * 1024);
    const u16* Vb2 = (const u16*)(ws + OFF_V2) + (size_t)bh * (64 * 512);
    const u16* Vb3 = (const u16*)(ws + OFF_V3) + (size_t)bh * (64 * 256);

    f16v oacc0[2], oacc1[2], oacc2[2], oacc3[2];
#pragma unroll
    for (int ht = 0; ht < 2; ht++)
#pragma unroll
        for (int r = 0; r < 16; r++) {
            oacc0[ht][r] = 0.f; oacc1[ht][r] = 0.f;
            oacc2[ht][r] = 0.f; oacc3[ht][r] = 0.f;
        }
    float ls0 = 0.f, ls1 = 0.f, ls2 = 0.f, ls3 = 0.f;

    // ---- prologue: direct-stage chunk 0; prefetch chunk 1 into regs
    *(uint4*)&KtB(0)[sr * 72 + sc8]       = *(const uint4*)(Kb + (size_t)sr * 64 + sc8);
    *(uint4*)&KtB(0)[sr * 72 + 32 + sc8]  = *(const uint4*)(Kb + (size_t)sr * 64 + 32 + sc8);
    *(uint4*)&V0B(0)[sr * 72 + sc8]       = *(const uint4*)(Vb0 + (size_t)sr * 2048 + sc8);
    *(uint4*)&V0B(0)[sr * 72 + 32 + sc8]  = *(const uint4*)(Vb0 + (size_t)sr * 2048 + 32 + sc8);
    *(uint4*)&V1B(0)[sr * 40 + sc8]       = *(const uint4*)(Vb1 + (size_t)sr * 1024 + sc8);
    *(uint2*)&V2B(0)[sr * 24 + vi4]       = *(const uint2*)(Vb2 + (size_t)sr * 512 + vi4);
    *(uint2*)&V3B(0)[sr * 24 + vi4]       = *(const uint2*)(Vb3 + (size_t)sr * 256 + vi4);
    uint4 kr0 = *(const uint4*)(Kb  + (size_t)(64 + sr) * 64 + sc8);
    uint4 kr1 = *(const uint4*)(Kb  + (size_t)(64 + sr) * 64 + 32 + sc8);
    uint4 vr0 = *(const uint4*)(Vb0 + (size_t)sr * 2048 + 64 + sc8);
    uint4 vr1 = *(const uint4*)(Vb0 + (size_t)sr * 2048 + 64 + 32 + sc8);
    uint4 v1r = *(const uint4*)(Vb1 + (size_t)sr * 1024 + 32 + sc8);
    uint2 v2r = *(const uint2*)(Vb2 + (size_t)sr * 512 + 16 + vi4);
    uint2 v3r = {};
    uint32_t cPaA = 0, cPbA = 0, cPaB = 0, cPbB = 0;
    __syncthreads();

    union uu { u32x4 u; bf8v b; };

    for (int jj = 0; jj < 32; jj += 2) {
        AITER(0)
        AITER(1)
    }

    // ---- fold the 4 scales: ofin = sum_s (w_s / ls_s) * oacc_s
    ls0 += __shfl_xor(ls0, 32);
    ls1 += __shfl_xor(ls1, 32);
    ls2 += __shfl_xor(ls2, 32);
    ls3 += __shfl_xor(ls3, 32);
    float4 sw = *(const float4*)&scw[(size_t)(b * SS + q) * 4];
    float w0 = sw.x / ls0, w1 = sw.y / ls1, w2 = sw.z / ls2, w3 = sw.w / ls3;

    const size_t base = (size_t)(b * SS + q) * 1024 + h * 64;
#pragma unroll
    for (int ht = 0; ht < 2; ht++)
#pragma unroll
        for (int g = 0; g < 4; g++) {
            float f0 = w0 * oacc0[ht][g * 4 + 0] + w1 * oacc1[ht][g * 4 + 0]
                     + w2 * oacc2[ht][g * 4 + 0] + w3 * oacc3[ht][g * 4 + 0];
            float f1 = w0 * oacc0[ht][g * 4 + 1] + w1 * oacc1[ht][g * 4 + 1]
                     + w2 * oacc2[ht][g * 4 + 1] + w3 * oacc3[ht][g * 4 + 1];
            float f2 = w0 * oacc0[ht][g * 4 + 2] + w1 * oacc1[ht][g * 4 + 2]
                     + w2 * oacc2[ht][g * 4 + 2] + w3 * oacc3[ht][g * 4 + 2];
            float f3 = w0 * oacc0[ht][g * 4 + 3] + w1 * oacc1[ht][g * 4 + 3]
                     + w2 * oacc2[ht][g * 4 + 3] + w3 * oacc3[ht][g * 4 + 3];
            uint2 pk;
            pk.x = pk2(f0, f1);
            pk.y = pk2(f2, f3);
            *(uint2*)&attnb[base + ht * 32 + g * 8 + half * 4] = pk;
        }
}

extern "C" void kernel_launch(void* const* d_in, const int* in_sizes, int n_in,
                              void* d_out, int out_size, void* d_ws, size_t ws_size,
                              hipStream_t stream) {
    const float* x      = (const float*)d_in[0];
    const float* Wqkv   = (const float*)d_in[1];
    const float* bqkv   = (const float*)d_in[2];
    const float* Wout   = (const float*)d_in[3];
    const float* bout   = (const float*)d_in[4];
    const float* Wscale = (const float*)d_in[5];
    const float* bscale = (const float*)d_in[6];
    float* out = (float*)d_out;

    char* ws = (char*)d_ws;
    u16*   wqt   = (u16*)(ws + OFF_WQT);
    u16*   wot   = (u16*)(ws + OFF_WOT);
    u16*   xb    = (u16*)(ws + OFF_XB);
    u16*   attnb = (u16*)(ws + OFF_Q);
    float* scw   = (float*)(ws + OFF_SCW);

    xconv_kernel<<<dim3(4096), dim3(256), 0, stream>>>(x, xb);
    wconv_kernel<<<dim3(48, 16), dim3(256), 0, stream>>>(Wqkv, wqt, 3072, 1024);
    wconv_kernel<<<dim3(16, 16), dim3(256), 0, stream>>>(Wout, wot, 1024, 1024);
    scale_kernel<<<dim3(1024), dim3(256), 0, stream>>>(x, Wscale, bscale, scw);
    gemm_bt<1><<<dim3(24, 32), dim3(256), 0, stream>>>(xb, wqt, bqkv, (void*)ws, 3072, 1024);
    attn_kernel<<<dim3(16, 16, 2), dim3(256), 0, stream>>>(ws);
    gemm_bt<0><<<dim3(8, 32), dim3(256), 0, stream>>>(attnb, wot, bout, (void*)out, 1024, 1024);
}

// Round 6
// 284.075 us; speedup vs baseline: 1.0999x; 1.0518x over previous
//
#include <hip/hip_runtime.h>
#include <stdint.h>

typedef unsigned short u16;
typedef __attribute__((ext_vector_type(8))) __bf16 bf8v;    // A/B fragment: 8 bf16
typedef __attribute__((ext_vector_type(4))) float f4v;      // 16x16 C/D
typedef __attribute__((ext_vector_type(16))) float f16v;    // 32x32 C/D
typedef __attribute__((ext_vector_type(4))) uint32_t u32x4;

#define BB 2
#define SS 2048
#define HH 1024

// workspace layout (bytes) — extent 56688640. V1/V2/V3 regions now unused.
#define OFF_Q   0u          // Q bf16 [4096][1024]; later attn output (same region)
#define OFF_K0  8388608u
#define OFF_V0  24117248u
#define OFF_WQT 39845888u   // Wqkv^T bf16 [3072][1024]  (6 MB)
#define OFF_WOT 46137344u   // Wout^T bf16 [1024][1024]  (2 MB)
#define OFF_XB  48234496u   // x bf16 [4096][1024]       (8 MB)
#define OFF_SCW 56623104u   // scale weights f32 [4096][4] (64 KB)

__device__ __forceinline__ u16 f2bf(float f) {
    union { float f; uint32_t u; } v; v.f = f;
    uint32_t r = v.u + 0x7fffu + ((v.u >> 16) & 1u);   // RNE
    return (u16)(r >> 16);
}
__device__ __forceinline__ uint32_t pk2(float a, float b) {
    return (uint32_t)f2bf(a) | ((uint32_t)f2bf(b) << 16);
}
// truncation pack (2 VALU): low half <- bf-trunc(a), high half <- bf-trunc(b)
__device__ __forceinline__ uint32_t pkt2(float a, float b) {
    union { float f; uint32_t u; } x, y; x.f = a; y.f = b;
    return (x.u >> 16) | (y.u & 0xffff0000u);
}
__device__ __forceinline__ bf8v u2b(uint4 v) {
    union { uint4 u; bf8v b; } x; x.u = v; return x.b;
}

// ---------------- x f32 -> bf16 ----------------
__global__ __launch_bounds__(256) void xconv_kernel(const float* __restrict__ x,
                                                    u16* __restrict__ xb) {
    size_t t = (size_t)blockIdx.x * 256 + threadIdx.x;
    float4 v = *(const float4*)&x[t * 4];
    uint2 pk; pk.x = pk2(v.x, v.y); pk.y = pk2(v.z, v.w);
    *(uint2*)&xb[t * 4] = pk;
}

// ---------------- W f32 [K][N] -> bf16 W^T [N][K] ----------------
__global__ __launch_bounds__(256) void wconv_kernel(const float* __restrict__ W,
                                                    u16* __restrict__ Wt,
                                                    int N, int K) {
    __shared__ float tile[64][69];
    const int tid = threadIdx.x;
    const int n0 = blockIdx.x * 64, k0 = blockIdx.y * 64;
    const int r = tid >> 4, c4 = (tid & 15) * 4;
#pragma unroll
    for (int it = 0; it < 4; it++) {
        float4 v = *(const float4*)&W[(size_t)(k0 + it * 16 + r) * N + n0 + c4];
        tile[it * 16 + r][c4 + 0] = v.x; tile[it * 16 + r][c4 + 1] = v.y;
        tile[it * 16 + r][c4 + 2] = v.z; tile[it * 16 + r][c4 + 3] = v.w;
    }
    __syncthreads();
#pragma unroll
    for (int it = 0; it < 4; it++) {
        int n = it * 16 + r;
        uint2 pk;
        pk.x = pk2(tile[c4 + 0][n], tile[c4 + 1][n]);
        pk.y = pk2(tile[c4 + 2][n], tile[c4 + 3][n]);
        *(uint2*)&Wt[(size_t)(n0 + n) * K + k0 + c4] = pk;
    }
}

// ---------------- scale weights: softmax(x @ Wscale + bscale) ----------------
__global__ __launch_bounds__(256) void scale_kernel(const float* __restrict__ x,
                                                    const float* __restrict__ Wscale,
                                                    const float* __restrict__ bscale,
                                                    float* __restrict__ scw) {
    const int lane = threadIdx.x & 63;
    const int wid  = threadIdx.x >> 6;
    const int row  = blockIdx.x * 4 + wid;
    float a0 = 0.f, a1 = 0.f, a2 = 0.f, a3 = 0.f;
    for (int i = 0; i < 16; i++) {
        int hh = lane + i * 64;
        float xs = x[(size_t)row * HH + hh];
        float4 wv = *(const float4*)&Wscale[hh * 4];
        a0 += xs * wv.x; a1 += xs * wv.y; a2 += xs * wv.z; a3 += xs * wv.w;
    }
    for (int off = 1; off < 64; off <<= 1) {
        a0 += __shfl_xor(a0, off); a1 += __shfl_xor(a1, off);
        a2 += __shfl_xor(a2, off); a3 += __shfl_xor(a3, off);
    }
    if (lane == 0) {
        a0 += bscale[0]; a1 += bscale[1]; a2 += bscale[2]; a3 += bscale[3];
        float mx = fmaxf(fmaxf(a0, a1), fmaxf(a2, a3));
        float e0 = __expf(a0 - mx), e1 = __expf(a1 - mx);
        float e2 = __expf(a2 - mx), e3 = __expf(a3 - mx);
        float inv = 1.f / (e0 + e1 + e2 + e3);
        float4 o = {e0 * inv, e1 * inv, e2 * inv, e3 * inv};
        *(float4*)&scw[(size_t)row * 4] = o;
    }
}

// ---------------- bf16 MFMA GEMM, A bf16, B pre-transposed bf16 ----------------
// MODE 0: C[M,N] f32 = A@B + bias.  MODE 1: QKV scatter epilogue.
// K scaled by 1/sqrt(64) * log2(e) so attn can use exp2 directly.
// V0 stored KEY-PERMUTED (bits 2<->3 of token) so attn PV B-fragments are
// lane-local (permuting the MFMA contraction index identically on both
// operands leaves the product unchanged).
template<int MODE>
__global__ __launch_bounds__(256) void gemm_bt(const u16* __restrict__ A,
                                               const u16* __restrict__ Bt,
                                               const float* __restrict__ bias,
                                               void* __restrict__ Cp,
                                               int N, int K) {
    __shared__ __align__(16) u16 At[128 * 40];
    __shared__ __align__(16) u16 Btl[128 * 40];
    const int tid  = threadIdx.x;
    const int lane = tid & 63;
    const int wid  = tid >> 6;
    const int l15  = lane & 15;
    const int quad = lane >> 4;
    const int wm = wid & 1, wn = wid >> 1;
    const int m0 = blockIdx.y * 128;
    const int n0 = blockIdx.x * 128;
    const int srow = tid >> 2;           // 0..63
    const int sc8  = (tid & 3) * 8;      // 0,8,16,24

    f4v acc[4][4];
#pragma unroll
    for (int i = 0; i < 4; i++)
#pragma unroll
        for (int j = 0; j < 4; j++) acc[i][j] = (f4v){0.f, 0.f, 0.f, 0.f};

    uint4 pa0 = *(const uint4*)(A  + (size_t)(m0 + srow) * K + sc8);
    uint4 pa1 = *(const uint4*)(A  + (size_t)(m0 + srow + 64) * K + sc8);
    uint4 pb0 = *(const uint4*)(Bt + (size_t)(n0 + srow) * K + sc8);
    uint4 pb1 = *(const uint4*)(Bt + (size_t)(n0 + srow + 64) * K + sc8);

    for (int kc = 0; kc < K; kc += 32) {
        __syncthreads();
        *(uint4*)&At[srow * 40 + sc8]         = pa0;
        *(uint4*)&At[(srow + 64) * 40 + sc8]  = pa1;
        *(uint4*)&Btl[srow * 40 + sc8]        = pb0;
        *(uint4*)&Btl[(srow + 64) * 40 + sc8] = pb1;
        __syncthreads();
        if (kc + 32 < K) {
            pa0 = *(const uint4*)(A  + (size_t)(m0 + srow) * K + kc + 32 + sc8);
            pa1 = *(const uint4*)(A  + (size_t)(m0 + srow + 64) * K + kc + 32 + sc8);
            pb0 = *(const uint4*)(Bt + (size_t)(n0 + srow) * K + kc + 32 + sc8);
            pb1 = *(const uint4*)(Bt + (size_t)(n0 + srow + 64) * K + kc + 32 + sc8);
        }
        bf8v af[4], bf[4];
#pragma unroll
        for (int t = 0; t < 4; t++) {
            af[t] = *(const bf8v*)&At[(wm * 64 + t * 16 + l15) * 40 + quad * 8];
            bf[t] = *(const bf8v*)&Btl[(wn * 64 + t * 16 + l15) * 40 + quad * 8];
        }
#pragma unroll
        for (int ti = 0; ti < 4; ti++)
#pragma unroll
            for (int tj = 0; tj < 4; tj++)
                acc[ti][tj] = __builtin_amdgcn_mfma_f32_16x16x32_bf16(af[ti], bf[tj], acc[ti][tj], 0, 0, 0);
    }

    if (MODE == 0) {
#pragma unroll
        for (int ti = 0; ti < 4; ti++)
#pragma unroll
            for (int tj = 0; tj < 4; tj++)
#pragma unroll
                for (int r = 0; r < 4; r++) {
                    int m = m0 + wm * 64 + ti * 16 + quad * 4 + r;
                    int n = n0 + wn * 64 + tj * 16 + l15;
                    ((float*)Cp)[(size_t)m * N + n] = acc[ti][tj][r] + bias[n];
                }
    } else {
        char* ws = (char*)Cp;
        u16* Qd = (u16*)ws;
        u16* K0 = (u16*)(ws + OFF_K0);
        u16* V0 = (u16*)(ws + OFF_V0);
        const int region = n0 >> 10;
        if (region == 0) {             // ---- Q dense bf16 [tok][h*64+hd]
#pragma unroll
            for (int ti = 0; ti < 4; ti++)
#pragma unroll
                for (int tj = 0; tj < 4; tj++)
#pragma unroll
                    for (int r = 0; r < 4; r++) {
                        int m = m0 + wm * 64 + ti * 16 + quad * 4 + r;
                        int n = n0 + wn * 64 + tj * 16 + l15;
                        Qd[(size_t)m * 1024 + n] = f2bf(acc[ti][tj][r] + bias[n]);
                    }
        } else if (region == 1) {      // ---- K, scale 0.125*log2(e)
#pragma unroll
            for (int ti = 0; ti < 4; ti++)
#pragma unroll
                for (int tj = 0; tj < 4; tj++) {
                    int n  = n0 + wn * 64 + tj * 16 + l15;
                    int nk = n - 1024;
                    int h = nk >> 6, hd = nk & 63;
#pragma unroll
                    for (int r = 0; r < 4; r++) {
                        int m = m0 + wm * 64 + ti * 16 + quad * 4 + r;
                        int bb = m >> 11, tok = m & 2047;
                        int bh = bb * 16 + h;
                        u16 bv = f2bf((acc[ti][tj][r] + bias[n]) * 0.18033688f);
                        K0[((size_t)bh * 2048 + tok) * 64 + hd] = bv;
                    }
                }
        } else {                       // ---- V^T [b,h,hd,tok], key-permuted
#pragma unroll
            for (int ti = 0; ti < 4; ti++)
#pragma unroll
                for (int tj = 0; tj < 4; tj++) {
                    int n  = n0 + wn * 64 + tj * 16 + l15;
                    int nv = n - 2048;
                    int h = nv >> 6, hd = nv & 63;
                    int tokb = m0 + wm * 64 + ti * 16 + quad * 4;
                    int bb = tokb >> 11, tok = tokb & 2047;
                    int bh = bb * 16 + h;
                    float v0 = acc[ti][tj][0] + bias[n];
                    float v1 = acc[ti][tj][1] + bias[n];
                    float v2 = acc[ti][tj][2] + bias[n];
                    float v3 = acc[ti][tj][3] + bias[n];
                    u16 c0 = f2bf(v0), c1 = f2bf(v1), c2 = f2bf(v2), c3 = f2bf(v3);
                    uint2 pk;
                    pk.x = (uint32_t)c0 | ((uint32_t)c1 << 16);
                    pk.y = (uint32_t)c2 | ((uint32_t)c3 << 16);
                    // V0: swap bits 2<->3 of token index (tok%4==0, run of 4 intact)
                    int tokp = (tok & ~15) | ((tok & 4) << 1) | ((tok & 8) >> 1);
                    *(uint2*)&V0[((size_t)bh * 64 + hd) * 2048 + tokp] = pk;
                }
        }
    }
}

// pass-2 iteration: QK from regs (KA), exp2 (weights pre-folded into C-init),
// pack, stage V0 c+1, prefetch V0 c+2 + K c+2, single PV vs V0, barrier.
#define PITER(C, KA, BUFC, BUFN)                                               \
    {                                                                          \
        const int c = (C);                                                     \
        f16v sa = sinit;                                                       \
        sa = __builtin_amdgcn_mfma_f32_32x32x16_bf16(u2b(KA[0]), qf[0], sa, 0, 0, 0); \
        sa = __builtin_amdgcn_mfma_f32_32x32x16_bf16(u2b(KA[1]), qf[1], sa, 0, 0, 0); \
        sa = __builtin_amdgcn_mfma_f32_32x32x16_bf16(u2b(KA[2]), qf[2], sa, 0, 0, 0); \
        sa = __builtin_amdgcn_mfma_f32_32x32x16_bf16(u2b(KA[3]), qf[3], sa, 0, 0, 0); \
        if (c + 2 < 64) {                                                      \
            _Pragma("unroll")                                                  \
            for (int ks = 0; ks < 4; ks++)                                     \
                KA[ks] = *(const uint4*)(Kb + (size_t)((c + 2) * 32 + l31) * 64 + ks * 16 + half * 8); \
        }                                                                      \
        if (c + 1 < 64) *(uint4*)&(BUFN)[sr * 40 + svk8] = vr;                 \
        if (c + 2 < 64) vr = *(const uint4*)(Vb0 + (size_t)sr * 2048 + (c + 2) * 32 + svk8); \
        uint32_t F0, F1, F2, F3, F4, F5, F6, F7;                               \
        {                                                                      \
            float x0, x1, x2, x3;                                              \
            x0 = exp2f(sa[0]);  x1 = exp2f(sa[1]);                             \
            x2 = exp2f(sa[2]);  x3 = exp2f(sa[3]);                             \
            F0 = pkt2(x0, x1); F1 = pkt2(x2, x3);                              \
            x0 = exp2f(sa[4]);  x1 = exp2f(sa[5]);                             \
            x2 = exp2f(sa[6]);  x3 = exp2f(sa[7]);                             \
            F2 = pkt2(x0, x1); F3 = pkt2(x2, x3);                              \
            x0 = exp2f(sa[8]);  x1 = exp2f(sa[9]);                             \
            x2 = exp2f(sa[10]); x3 = exp2f(sa[11]);                            \
            F4 = pkt2(x0, x1); F5 = pkt2(x2, x3);                              \
            x0 = exp2f(sa[12]); x1 = exp2f(sa[13]);                            \
            x2 = exp2f(sa[14]); x3 = exp2f(sa[15]);                            \
            F6 = pkt2(x0, x1); F7 = pkt2(x2, x3);                              \
        }                                                                      \
        uu p0; p0.u = (u32x4){F0, F1, F2, F3};                                 \
        uu p1; p1.u = (u32x4){F4, F5, F6, F7};                                 \
        bf8v va00 = *(const bf8v*)&(BUFC)[l31 * 40 + half * 8];                \
        oacc[0] = __builtin_amdgcn_mfma_f32_32x32x16_bf16(va00, p0.b, oacc[0], 0, 0, 0); \
        bf8v va01 = *(const bf8v*)&(BUFC)[l31 * 40 + 16 + half * 8];           \
        oacc[0] = __builtin_amdgcn_mfma_f32_32x32x16_bf16(va01, p1.b, oacc[0], 0, 0, 0); \
        bf8v va10 = *(const bf8v*)&(BUFC)[(32 + l31) * 40 + half * 8];         \
        oacc[1] = __builtin_amdgcn_mfma_f32_32x32x16_bf16(va10, p0.b, oacc[1], 0, 0, 0); \
        bf8v va11 = *(const bf8v*)&(BUFC)[(32 + l31) * 40 + 16 + half * 8];    \
        oacc[1] = __builtin_amdgcn_mfma_f32_32x32x16_bf16(va11, p1.b, oacc[1], 0, 0, 0); \
        __syncthreads();                                                       \
    }

// ---------------- multi-scale attention: two-pass, single accumulator ----------
// out = sum_k e[k]*M[k]*V[k], M[k] = w0/ls0 + [k%2==0]w1/ls1 + [k%4==0]w2/ls2
//       + [k%8==0]w3/ls3.
// Pass 1: QK + exp + ls0..3 only. K fragments are per-lane global loads
//   (prefetched 2 chunks deep) — no LDS, no barriers, chunks independent.
// Pass 2: log2(M) folded into the QK MFMA C-input (exp2(sa) = M*e), single PV
//   vs key-permuted V0 (fragments lane-local, verified r3 mapping).
// Registers: oacc 32 + qf 16 + K prefetch 32 + misc ~50 -> no spill possible.
__global__ __launch_bounds__(256, 2) void attn_kernel(const char* __restrict__ ws) {
    __shared__ __align__(16) u16 smem[5120];   // V0 tile [64][40] x2 = 10 KB
    u16* Vt0 = smem;
    u16* Vt1 = smem + 2560;

    const u16* Qd    = (const u16*)(ws + OFF_Q);
    const float* scw = (const float*)(ws + OFF_SCW);
    u16* attnb       = (u16*)(ws + OFF_Q);          // aliases Q (block reads Q first)

    const int tid  = threadIdx.x;
    const int lane = tid & 63;
    const int wid  = tid >> 6;
    const int l31  = lane & 31;
    const int half = lane >> 5;

    // XCD-aware swizzle (bijective on 512 blocks): 4 (b,h) groups per XCD.
    const int f   = blockIdx.x + 16 * blockIdx.y + 256 * blockIdx.z;  // 0..511
    const int xcd = f & 7, jj = f >> 3;
    const int grp = xcd * 4 + (jj >> 4);    // 0..31 = (b,h)
    const int qt  = jj & 15;
    const int b = grp >> 4, h = grp & 15;
    const int q  = qt * 128 + wid * 32 + l31;
    const int bh = b * 16 + h;

    const int sr   = tid >> 2;             // 0..63 (V0 staging row = hd)
    const int svk8 = (tid & 3) * 8;        // 0,8,16,24

    // Q B-frags: qf[ks] = Q[q][h*64 + ks*16 + half*8 + j]
    bf8v qf[4];
#pragma unroll
    for (int ks = 0; ks < 4; ks++)
        qf[ks] = *(const bf8v*)(Qd + (size_t)(b * SS + q) * 1024 + h * 64 + ks * 16 + half * 8);

    const u16* Kb  = (const u16*)(ws + OFF_K0) + (size_t)bh * (2048 * 64);
    const u16* Vb0 = (const u16*)(ws + OFF_V0) + (size_t)bh * (64 * 2048);

    union uu { u32x4 u; bf8v b; };

    // ================= pass 1: ls0..3 =================
    float ls0 = 0.f, ls1 = 0.f, ls2 = 0.f, ls3 = 0.f;
    uint4 kp[4], kq[4];
#pragma unroll
    for (int ks = 0; ks < 4; ks++) {
        kp[ks] = *(const uint4*)(Kb + (size_t)l31 * 64 + ks * 16 + half * 8);
        kq[ks] = *(const uint4*)(Kb + (size_t)(32 + l31) * 64 + ks * 16 + half * 8);
    }
    for (int c = 0; c < 64; c += 2) {
        f16v sA = {0,0,0,0,0,0,0,0,0,0,0,0,0,0,0,0};
        f16v sB = {0,0,0,0,0,0,0,0,0,0,0,0,0,0,0,0};
#pragma unroll
        for (int ks = 0; ks < 4; ks++) {
            sA = __builtin_amdgcn_mfma_f32_32x32x16_bf16(u2b(kp[ks]), qf[ks], sA, 0, 0, 0);
            sB = __builtin_amdgcn_mfma_f32_32x32x16_bf16(u2b(kq[ks]), qf[ks], sB, 0, 0, 0);
        }
        if (c + 2 < 64) {
#pragma unroll
            for (int ks = 0; ks < 4; ks++)
                kp[ks] = *(const uint4*)(Kb + (size_t)((c + 2) * 32 + l31) * 64 + ks * 16 + half * 8);
#pragma unroll
            for (int ks = 0; ks < 4; ks++)
                kq[ks] = *(const uint4*)(Kb + (size_t)((c + 3) * 32 + l31) * 64 + ks * 16 + half * 8);
        }
#pragma unroll
        for (int g = 0; g < 4; g++) {
            float x0 = exp2f(sA[4 * g + 0]);
            float x1 = exp2f(sA[4 * g + 1]);
            float x2 = exp2f(sA[4 * g + 2]);
            float x3 = exp2f(sA[4 * g + 3]);
            ls0 += (x0 + x1) + (x2 + x3);
            ls1 += x0 + x2;
            ls2 += x0;
            if (!half) ls3 += x0;
        }
#pragma unroll
        for (int g = 0; g < 4; g++) {
            float x0 = exp2f(sB[4 * g + 0]);
            float x1 = exp2f(sB[4 * g + 1]);
            float x2 = exp2f(sB[4 * g + 2]);
            float x3 = exp2f(sB[4 * g + 3]);
            ls0 += (x0 + x1) + (x2 + x3);
            ls1 += x0 + x2;
            ls2 += x0;
            if (!half) ls3 += x0;
        }
    }
    ls0 += __shfl_xor(ls0, 32);
    ls1 += __shfl_xor(ls1, 32);
    ls2 += __shfl_xor(ls2, 32);
    ls3 += __shfl_xor(ls3, 32);

    // ---- per-lane combined multipliers (key = 8g + 4*half + i):
    //   i odd -> m = w0/ls0; i==2 -> +w1/ls1; i==0 -> +w2/ls2 (+w3/ls3 if half==0)
    float4 sw = *(const float4*)&scw[(size_t)(b * SS + q) * 4];
    float m0v = sw.x / ls0;
    float m2v = m0v + sw.y / ls1;
    float mAv = m2v + sw.z / ls2;
    float mBv = mAv + sw.w / ls3;
    float lmO = log2f(m0v);
    float lmE = log2f(m2v);
    float lmZ = log2f(half ? mAv : mBv);
    f16v sinit;
#pragma unroll
    for (int g = 0; g < 4; g++) {
        sinit[4 * g + 0] = lmZ; sinit[4 * g + 1] = lmO;
        sinit[4 * g + 2] = lmE; sinit[4 * g + 3] = lmO;
    }

    // ================= pass 2: PV =================
    f16v oacc[2];
#pragma unroll
    for (int ht = 0; ht < 2; ht++)
#pragma unroll
        for (int r = 0; r < 16; r++) oacc[ht][r] = 0.f;

    // prologue: stage V0 chunk 0; prefetch V0 chunk 1 + K chunks 0,1
    *(uint4*)&Vt0[sr * 40 + svk8] = *(const uint4*)(Vb0 + (size_t)sr * 2048 + svk8);
    uint4 vr = *(const uint4*)(Vb0 + (size_t)sr * 2048 + 32 + svk8);
#pragma unroll
    for (int ks = 0; ks < 4; ks++) {
        kp[ks] = *(const uint4*)(Kb + (size_t)l31 * 64 + ks * 16 + half * 8);
        kq[ks] = *(const uint4*)(Kb + (size_t)(32 + l31) * 64 + ks * 16 + half * 8);
    }
    __syncthreads();

    for (int cc = 0; cc < 64; cc += 2) {
        PITER(cc,     kp, Vt0, Vt1)
        PITER(cc + 1, kq, Vt1, Vt0)
    }

    // ---- output (weights already folded into P)
    const size_t base = (size_t)(b * SS + q) * 1024 + h * 64;
#pragma unroll
    for (int ht = 0; ht < 2; ht++)
#pragma unroll
        for (int g = 0; g < 4; g++) {
            uint2 pk;
            pk.x = pk2(oacc[ht][g * 4 + 0], oacc[ht][g * 4 + 1]);
            pk.y = pk2(oacc[ht][g * 4 + 2], oacc[ht][g * 4 + 3]);
            *(uint2*)&attnb[base + ht * 32 + g * 8 + half * 4] = pk;
        }
}

extern "C" void kernel_launch(void* const* d_in, const int* in_sizes, int n_in,
                              void* d_out, int out_size, void* d_ws, size_t ws_size,
                              hipStream_t stream) {
    const float* x      = (const float*)d_in[0];
    const float* Wqkv   = (const float*)d_in[1];
    const float* bqkv   = (const float*)d_in[2];
    const float* Wout   = (const float*)d_in[3];
    const float* bout   = (const float*)d_in[4];
    const float* Wscale = (const float*)d_in[5];
    const float* bscale = (const float*)d_in[6];
    float* out = (float*)d_out;

    char* ws = (char*)d_ws;
    u16*   wqt   = (u16*)(ws + OFF_WQT);
    u16*   wot   = (u16*)(ws + OFF_WOT);
    u16*   xb    = (u16*)(ws + OFF_XB);
    u16*   attnb = (u16*)(ws + OFF_Q);
    float* scw   = (float*)(ws + OFF_SCW);

    xconv_kernel<<<dim3(4096), dim3(256), 0, stream>>>(x, xb);
    wconv_kernel<<<dim3(48, 16), dim3(256), 0, stream>>>(Wqkv, wqt, 3072, 1024);
    wconv_kernel<<<dim3(16, 16), dim3(256), 0, stream>>>(Wout, wot, 1024, 1024);
    scale_kernel<<<dim3(1024), dim3(256), 0, stream>>>(x, Wscale, bscale, scw);
    gemm_bt<1><<<dim3(24, 32), dim3(256), 0, stream>>>(xb, wqt, bqkv, (void*)ws, 3072, 1024);
    attn_kernel<<<dim3(16, 16, 2), dim3(256), 0, stream>>>(ws);
    gemm_bt<0><<<dim3(8, 32), dim3(256), 0, stream>>>(attnb, wot, bout, (void*)out, 1024, 1024);
}